// Round 10
// baseline (17.264 us; speedup 1.0000x reference)
//
#include <hip/hip_runtime.h>
#include <math.h>

#define B_SZ   512
#define M_MIX  32
#define D_DIM  1024
#define T_MAX  4096
#define P3M    96            // 3 * M_MIX
#define RPB    4             // batch rows per block
#define NBLK   (B_SZ / RPB)  // 128 blocks
#define NTHR   1024
#define KQ     8             // in-block k-split
#define KCH    (D_DIM / KQ)  // 128

typedef float vf4 __attribute__((ext_vector_type(4)));

// ---------------------------------------------------------------------------
// Single-node fused kernel, zero cross-block deps, no workspace.
// 128 blocks x 1024 threads, RPB=4 rows per block:
//   - W redundancy halved vs RPB=2: 128 x 384 KB = 49 MB XCD-local L2 reads
//   - B phase: 768 active threads = 12 waves = 3/SIMD (latency hiding x2)
//   A) stage q[4][1024] in LDS (float4) + zero-fill own 4 output rows (NT)
//   B) GEMM: j=0..95 x kq=0..7, 128-long dots, q via LDS broadcast
//   C) reduce partials + transform to alpha / -beta*log2e / kappa / radius
//   D) per-row window min/max (wave reduce, mixtures duplicated)
//   E) phi with wave-uniform window skip; stores ONLY i-blocks intersecting
//      [0, gmax] (rest provably < e^-37, already zeroed in A)
// ---------------------------------------------------------------------------
__global__ __launch_bounds__(NTHR) void fused_kernel(
    const float* __restrict__ query,
    const float* __restrict__ prev_kappa,
    const float* __restrict__ W,
    const float* __restrict__ bias,
    const int* __restrict__ seqlen,
    float* __restrict__ out)
{
    __shared__ float sQ[RPB][D_DIM];      // 16 KB
    __shared__ float sP[KQ][RPB][P3M];    // 12 KB partials
    __shared__ float sA[RPB][M_MIX];      // alpha
    __shared__ float sC[RPB][M_MIX];      // -beta * log2(e)
    __shared__ float sK[RPB][M_MIX];      // kappa
    __shared__ float sR[RPB][M_MIX];      // half-width sqrt(37/beta)
    __shared__ float sRange[RPB][2];
    __shared__ float sRed[RPB][4];
    __shared__ int   sL[RPB];

    const int tid = threadIdx.x;
    const int b0  = blockIdx.x * RPB;

    // ---- A: stage q (1024 thr x one float4) + zero-fill own output rows ----
    {
        const int r = tid >> 8;           // 256 float4 per row
        const int c = tid & 255;
        reinterpret_cast<float4*>(&sQ[r][0])[c] =
            reinterpret_cast<const float4*>(query + (size_t)(b0 + r) * D_DIM)[c];
    }
    if (tid < RPB) sL[tid] = seqlen[b0 + tid];
    {
        // own 4 rows = 4*4096 floats = 4096 vf4; 1024 thr x 4 NT stores
        vf4* oz = reinterpret_cast<vf4*>(out + (size_t)b0 * T_MAX);
        const vf4 z = {0.f, 0.f, 0.f, 0.f};
        #pragma unroll
        for (int i = 0; i < 4; ++i)
            __builtin_nontemporal_store(z, oz + tid + i * NTHR);
    }
    __syncthreads();

    // ---- B: k-split dots. W coalesced over j; q via LDS broadcast ----
    if (tid < KQ * P3M) {
        const int j  = tid % P3M;
        const int kq = tid / P3M;
        const float* Wp = W + (size_t)(kq * KCH) * P3M + j;
        const float* q0 = &sQ[0][kq * KCH];
        const float* q1 = &sQ[1][kq * KCH];
        const float* q2 = &sQ[2][kq * KCH];
        const float* q3 = &sQ[3][kq * KCH];
        float a0 = 0.f, a1 = 0.f, a2 = 0.f, a3 = 0.f;
        #pragma unroll 8
        for (int d = 0; d < KCH; ++d) {
            const float w = Wp[(size_t)d * P3M];
            a0 = fmaf(q0[d], w, a0);
            a1 = fmaf(q1[d], w, a1);
            a2 = fmaf(q2[d], w, a2);
            a3 = fmaf(q3[d], w, a3);
        }
        sP[kq][0][j] = a0; sP[kq][1][j] = a1;
        sP[kq][2][j] = a2; sP[kq][3][j] = a3;
    }
    __syncthreads();

    // ---- C: reduce + transform (384 threads: r = tid/96, j = tid%96) ----
    if (tid < RPB * P3M) {
        const int r = tid / P3M, j = tid % P3M;
        float p = bias[j];
        #pragma unroll
        for (int kq = 0; kq < KQ; ++kq) p += sP[kq][r][j];
        const int m = j & 31;
        if (j < M_MIX) {
            sA[r][m] = __expf(p);
        } else if (j < 2 * M_MIX) {
            const float be = __expf(p);
            sC[r][m] = -be * 1.44269504f;
            sR[r][m] = 6.0827625f * __frsqrt_rn(be);   // sqrt(37/beta)
        } else {
            const float ka = prev_kappa[(size_t)(b0 + r) * M_MIX + m] + __expf(p);
            sK[r][m] = ka;
            out[(size_t)B_SZ * T_MAX + (size_t)(b0 + r) * M_MIX + m] = ka;
        }
    }
    __syncthreads();

    // ---- D: per-row window reduce; wave r handles row r ----
    if (tid < RPB * 64) {
        const int r = tid >> 6;
        const int m = tid & 31;     // mixtures duplicated across 64 lanes
        float lo = sK[r][m] - sR[r][m];
        float hi = sK[r][m] + sR[r][m];
        #pragma unroll
        for (int off = 32; off >= 1; off >>= 1) {
            lo = fminf(lo, __shfl_xor(lo, off));
            hi = fmaxf(hi, __shfl_xor(hi, off));
        }
        if ((tid & 63) == 0) { sRange[r][0] = lo; sRange[r][1] = hi; }
    }
    __syncthreads();

    // ---- E: phi for row r = tid>>8, t = (tid&255) + 256*i ----
    const int   r     = tid >> 8;
    const int   lt    = tid & 255;
    const float gmin  = sRange[r][0], gmax = sRange[r][1];
    const int   wbase = lt & ~63;
    const float tf    = (float)lt;

    float acc[16];
    #pragma unroll
    for (int i = 0; i < 16; ++i) acc[i] = 0.f;

    #pragma unroll
    for (int i = 0; i < 16; ++i) {
        const float wlo = (float)(wbase + i * 256);
        if (gmax >= wlo && gmin <= wlo + 63.0f) {   // wave-uniform skip
            const float t = tf + (float)(i * 256);
            #pragma unroll 4
            for (int m = 0; m < M_MIX; ++m) {
                const float d = sK[r][m] - t;
                acc[i] += sA[r][m] * exp2f(sC[r][m] * d * d);
            }
        }
    }

    // mask + per-thread sum
    const int L = sL[r];
    float s = 0.f;
    #pragma unroll
    for (int i = 0; i < 16; ++i) {
        const int t = lt + i * 256;
        if (t >= L) acc[i] = 0.f;
        s += acc[i];
    }
    #pragma unroll
    for (int off = 32; off >= 1; off >>= 1) s += __shfl_xor(s, off);
    if ((tid & 63) == 0) sRed[r][(tid >> 6) & 3] = s;
    __syncthreads();
    const float invn = 1.0f /
        (sRed[r][0] + sRed[r][1] + sRed[r][2] + sRed[r][3] + 1e-8f);

    // stores: only i-blocks intersecting [0, gmax]; rest already zeroed in A
    int nI = __float2int_rz(gmax * (1.0f / 256.0f)) + 1;
    nI = (nI < 1) ? 1 : (nI > 16) ? 16 : nI;

    float* ob = out + (size_t)(b0 + r) * T_MAX;
    #pragma unroll
    for (int i = 0; i < 16; ++i)
        if (i < nI)
            __builtin_nontemporal_store(acc[i] * invn, ob + lt + i * 256);
}

extern "C" void kernel_launch(void* const* d_in, const int* in_sizes, int n_in,
                              void* d_out, int out_size, void* d_ws, size_t ws_size,
                              hipStream_t stream) {
    const float* query = (const float*)d_in[0];
    const float* prevk = (const float*)d_in[1];
    const float* W     = (const float*)d_in[2];
    const float* bias  = (const float*)d_in[3];
    const int*   msl   = (const int*)d_in[4];
    float* out = (float*)d_out;
    (void)d_ws; (void)ws_size;

    fused_kernel<<<NBLK, NTHR, 0, stream>>>(query, prevk, W, bias, msl, out);
}

// Round 11
// 13.988 us; speedup vs baseline: 1.2343x; 1.2343x over previous
//
#include <hip/hip_runtime.h>
#include <math.h>

#define B_SZ   512
#define M_MIX  32
#define D_DIM  1024
#define T_MAX  4096
#define P3M    96            // 3 * M_MIX
#define RPB    2             // batch rows per block
#define NBLK   (B_SZ / RPB)  // 256 blocks = 1 per CU
#define NTHR   512
#define KQ     16            // in-block k-split
#define KCH    (D_DIM / KQ)  // 64
#define JQ     (P3M / 4)     // 24 j-quads

typedef float vf4 __attribute__((ext_vector_type(4)));

// ---------------------------------------------------------------------------
// Single-node fused kernel, zero cross-block deps, no workspace.
// 256 blocks x 512 threads = 1 block/CU. Block owns RPB=2 rows end-to-end.
//   A) stage q[2][1024] in LDS (float4) + zero-fill own 2 output rows (NT)
//   B) GEMM: thread = (j-quad 0..23, kq 0..15) -> 384 thr; 64 float4 W loads
//      per thread (vectorized; 4x fewer load insts than scalar-j version),
//      8 FMAs per load into vf4 accumulators; partials to LDS
//   C) reduce 16 partials + transform to alpha / -beta*log2e / kappa / radius
//   D) per-row window min/max (wave reduce, mixtures duplicated)
//   E) phi with wave-uniform window skip; stores ONLY i-blocks intersecting
//      [0, gmax] (rest provably < e^-37, already zeroed in A)
// ---------------------------------------------------------------------------
__global__ __launch_bounds__(NTHR) void fused_kernel(
    const float* __restrict__ query,
    const float* __restrict__ prev_kappa,
    const float* __restrict__ W,
    const float* __restrict__ bias,
    const int* __restrict__ seqlen,
    float* __restrict__ out)
{
    __shared__ float sQ[RPB][D_DIM];      // 8 KB
    __shared__ float sP[KQ][RPB][P3M];    // 12 KB partials
    __shared__ float sA[RPB][M_MIX];      // alpha
    __shared__ float sC[RPB][M_MIX];      // -beta * log2(e)
    __shared__ float sK[RPB][M_MIX];      // kappa
    __shared__ float sR[RPB][M_MIX];      // half-width sqrt(37/beta)
    __shared__ float sRange[RPB][2];
    __shared__ float sRed[RPB][4];
    __shared__ int   sL[RPB];

    const int tid = threadIdx.x;
    const int b0  = blockIdx.x * RPB;

    // ---- A: stage q (512 thr x one float4) + zero-fill own output rows ----
    {
        const int r = tid >> 8;           // 256 float4 per row
        const int c = tid & 255;
        reinterpret_cast<float4*>(&sQ[r][0])[c] =
            reinterpret_cast<const float4*>(query + (size_t)(b0 + r) * D_DIM)[c];
    }
    if (tid < RPB) sL[tid] = seqlen[b0 + tid];
    {
        // own 2 rows = 2*4096 floats = 2048 vf4; 512 thr x 4 NT stores
        vf4* oz = reinterpret_cast<vf4*>(out + (size_t)b0 * T_MAX);
        const vf4 z = {0.f, 0.f, 0.f, 0.f};
        #pragma unroll
        for (int i = 0; i < 4; ++i)
            __builtin_nontemporal_store(z, oz + tid + i * NTHR);
    }
    __syncthreads();

    // ---- B: vectorized k-split dots (384 thr: jq = tid%24, kq = tid/24) ----
    if (tid < JQ * KQ) {
        const int jq = tid % JQ;
        const int kq = tid / JQ;
        const float* Wp = W + (size_t)(kq * KCH) * P3M + jq * 4;
        const float* q0 = &sQ[0][kq * KCH];
        const float* q1 = &sQ[1][kq * KCH];
        vf4 a0 = {0.f, 0.f, 0.f, 0.f};
        vf4 a1 = {0.f, 0.f, 0.f, 0.f};
        #pragma unroll 8
        for (int d = 0; d < KCH; ++d) {
            const vf4 w = *reinterpret_cast<const vf4*>(Wp + (size_t)d * P3M);
            a0 += w * q0[d];
            a1 += w * q1[d];
        }
        *reinterpret_cast<vf4*>(&sP[kq][0][jq * 4]) = a0;
        *reinterpret_cast<vf4*>(&sP[kq][1][jq * 4]) = a1;
    }
    __syncthreads();

    // ---- C: reduce + transform (192 threads: r = tid/96, j = tid%96) ----
    if (tid < RPB * P3M) {
        const int r = tid / P3M, j = tid % P3M;
        float p = bias[j];
        #pragma unroll
        for (int kq = 0; kq < KQ; ++kq) p += sP[kq][r][j];
        const int m = j & 31;
        if (j < M_MIX) {
            sA[r][m] = __expf(p);
        } else if (j < 2 * M_MIX) {
            const float be = __expf(p);
            sC[r][m] = -be * 1.44269504f;
            sR[r][m] = 6.0827625f * __frsqrt_rn(be);   // sqrt(37/beta)
        } else {
            const float ka = prev_kappa[(size_t)(b0 + r) * M_MIX + m] + __expf(p);
            sK[r][m] = ka;
            out[(size_t)B_SZ * T_MAX + (size_t)(b0 + r) * M_MIX + m] = ka;
        }
    }
    __syncthreads();

    // ---- D: per-row window reduce; wave r handles row r ----
    if (tid < RPB * 64) {
        const int r = tid >> 6;
        const int m = tid & 31;     // mixtures duplicated across 64 lanes
        float lo = sK[r][m] - sR[r][m];
        float hi = sK[r][m] + sR[r][m];
        #pragma unroll
        for (int off = 32; off >= 1; off >>= 1) {
            lo = fminf(lo, __shfl_xor(lo, off));
            hi = fmaxf(hi, __shfl_xor(hi, off));
        }
        if ((tid & 63) == 0) { sRange[r][0] = lo; sRange[r][1] = hi; }
    }
    __syncthreads();

    // ---- E: phi for row r = tid>>8, t = (tid&255) + 256*i ----
    const int   r     = tid >> 8;
    const int   lt    = tid & 255;
    const float gmin  = sRange[r][0], gmax = sRange[r][1];
    const int   wbase = lt & ~63;
    const float tf    = (float)lt;

    float acc[16];
    #pragma unroll
    for (int i = 0; i < 16; ++i) acc[i] = 0.f;

    #pragma unroll
    for (int i = 0; i < 16; ++i) {
        const float wlo = (float)(wbase + i * 256);
        if (gmax >= wlo && gmin <= wlo + 63.0f) {   // wave-uniform skip
            const float t = tf + (float)(i * 256);
            #pragma unroll 4
            for (int m = 0; m < M_MIX; ++m) {
                const float d = sK[r][m] - t;
                acc[i] += sA[r][m] * exp2f(sC[r][m] * d * d);
            }
        }
    }

    // mask + per-thread sum
    const int L = sL[r];
    float s = 0.f;
    #pragma unroll
    for (int i = 0; i < 16; ++i) {
        const int t = lt + i * 256;
        if (t >= L) acc[i] = 0.f;
        s += acc[i];
    }
    #pragma unroll
    for (int off = 32; off >= 1; off >>= 1) s += __shfl_xor(s, off);
    if ((tid & 63) == 0) sRed[r][(tid >> 6) & 3] = s;
    __syncthreads();
    const float invn = 1.0f /
        (sRed[r][0] + sRed[r][1] + sRed[r][2] + sRed[r][3] + 1e-8f);

    // stores: only i-blocks intersecting [0, gmax]; rest already zeroed in A
    int nI = __float2int_rz(gmax * (1.0f / 256.0f)) + 1;
    nI = (nI < 1) ? 1 : (nI > 16) ? 16 : nI;

    float* ob = out + (size_t)(b0 + r) * T_MAX;
    #pragma unroll
    for (int i = 0; i < 16; ++i)
        if (i < nI)
            __builtin_nontemporal_store(acc[i] * invn, ob + lt + i * 256);
}

extern "C" void kernel_launch(void* const* d_in, const int* in_sizes, int n_in,
                              void* d_out, int out_size, void* d_ws, size_t ws_size,
                              hipStream_t stream) {
    const float* query = (const float*)d_in[0];
    const float* prevk = (const float*)d_in[1];
    const float* W     = (const float*)d_in[2];
    const float* bias  = (const float*)d_in[3];
    const int*   msl   = (const int*)d_in[4];
    float* out = (float*)d_out;
    (void)d_ws; (void)ws_size;

    fused_kernel<<<NBLK, NTHR, 0, stream>>>(query, prevk, W, bias, msl, out);
}